// Round 1
// baseline (181.744 us; speedup 1.0000x reference)
//
#include <hip/hip_runtime.h>
#include <hip/hip_bf16.h>

typedef unsigned short u16;
typedef __attribute__((ext_vector_type(4))) float f32x4;
typedef __attribute__((ext_vector_type(8))) short bf16x8;

#define DEVI static __device__ __forceinline__

DEVI u16 f2bf(float f) {
  __hip_bfloat16 h = __float2bfloat16(f);
  return *reinterpret_cast<u16*>(&h);
}
DEVI float bf2f(u16 u) {
  unsigned int x = ((unsigned int)u) << 16;
  return __uint_as_float(x);
}

// global -> LDS direct DMA, 16B per lane. LDS dest is wave-uniform base + lane*16.
DEVI void gload_lds16(const void* g, void* l) {
  __builtin_amdgcn_global_load_lds(
      (const __attribute__((address_space(1))) unsigned int*)g,
      (__attribute__((address_space(3))) unsigned int*)l, 16, 0, 0);
}

// ---------------- f32 -> bf16 conversion ----------------
__global__ __launch_bounds__(256) void k_conv(const float* __restrict__ s,
                                              u16* __restrict__ d, int n) {
  int i = (blockIdx.x * 256 + threadIdx.x) * 8;
  if (i >= n) return;
  f32x4 a = *(const f32x4*)(s + i);
  f32x4 b = *(const f32x4*)(s + i + 4);
  bf16x8 v;
#pragma unroll
  for (int j = 0; j < 4; ++j) {
    v[j]     = (short)f2bf(a[j]);
    v[4 + j] = (short)f2bf(b[j]);
  }
  *(bf16x8*)(d + i) = v;
}

__global__ __launch_bounds__(256) void k_convw(const float* __restrict__ w0,
                                               const float* __restrict__ w1,
                                               const float* __restrict__ w2,
                                               const float* __restrict__ w3,
                                               u16* __restrict__ d) {
  int t = blockIdx.x * 256 + threadIdx.x;  // 131072 threads total
  int which = t >> 15;                     // 32768 threads per 262144-elem weight
  int i = (t & 32767) * 8;
  const float* s = which == 0 ? w0 : which == 1 ? w1 : which == 2 ? w2 : w3;
  f32x4 a = *(const f32x4*)(s + i);
  f32x4 b = *(const f32x4*)(s + i + 4);
  bf16x8 v;
#pragma unroll
  for (int j = 0; j < 4; ++j) {
    v[j]     = (short)f2bf(a[j]);
    v[4 + j] = (short)f2bf(b[j]);
  }
  *(bf16x8*)(d + (size_t)which * 262144 + i) = v;
}

// ---------------- GEMM: C[M][512] = A[M][512] @ W[512][512]^T + bias ----------------
// A, W bf16; acc f32. BM=128 BN=64 BK=64, 4 waves (2x2), wave tile 64x32.
// MODE 0: write bf16 to [B][H][N][64]   (Q, K)
// MODE 1: write bf16 to [B][H][64][N]   (V transposed)
// MODE 2: write f32 row-major [M][512]  (final output)
template <int MODE>
__global__ __launch_bounds__(256) void k_gemm(const u16* __restrict__ A,
                                              const u16* __restrict__ Bw,
                                              const float* __restrict__ bias,
                                              void* __restrict__ Cout) {
  constexpr int K = 512;
  __shared__ __align__(16) u16 As[128 * 64];  // 16KB, swizzled
  __shared__ __align__(16) u16 Bs[64 * 64];   // 8KB, swizzled
  const int tid = threadIdx.x;
  const int wid = tid >> 6, lane = tid & 63;
  const int g = lane >> 4, li = lane & 15;
  const int wr = wid >> 1, wc = wid & 1;
  const int m0 = blockIdx.y * 128, n0 = blockIdx.x * 64;

  f32x4 acc[4][2] = {};

  for (int kt = 0; kt < K / 64; ++kt) {
    const int k0 = kt * 64;
    // stage A tile (16KB): linear LDS dest, inverse-swizzled global src
#pragma unroll
    for (int i = 0; i < 4; ++i) {
      int P0 = ((i * 4 + wid) << 10) + lane * 16;
      int L0 = P0 ^ (((P0 >> 7) & 7) << 4);
      int row = L0 >> 7, colb = L0 & 127;
      gload_lds16((const char*)A + ((size_t)(m0 + row) * K + k0) * 2 + colb,
                  (char*)As + ((i * 4 + wid) << 10));
    }
    // stage B tile (8KB)
#pragma unroll
    for (int i = 0; i < 2; ++i) {
      int P0 = ((i * 4 + wid) << 10) + lane * 16;
      int L0 = P0 ^ (((P0 >> 7) & 7) << 4);
      int row = L0 >> 7, colb = L0 & 127;
      gload_lds16((const char*)Bw + ((size_t)(n0 + row) * K + k0) * 2 + colb,
                  (char*)Bs + ((i * 4 + wid) << 10));
    }
    asm volatile("s_waitcnt vmcnt(0)" ::: "memory");
    __syncthreads();

#pragma unroll
    for (int ks = 0; ks < 2; ++ks) {
      bf16x8 af[4], bfr[2];
#pragma unroll
      for (int mr = 0; mr < 4; ++mr) {
        int row = wr * 64 + mr * 16 + li;
        int L = row * 128 + ks * 64 + g * 16;
        int P = L ^ ((row & 7) << 4);
        af[mr] = *(const bf16x8*)((const char*)As + P);
      }
#pragma unroll
      for (int nr = 0; nr < 2; ++nr) {
        int row = wc * 32 + nr * 16 + li;
        int L = row * 128 + ks * 64 + g * 16;
        int P = L ^ ((row & 7) << 4);
        bfr[nr] = *(const bf16x8*)((const char*)Bs + P);
      }
#pragma unroll
      for (int mr = 0; mr < 4; ++mr)
#pragma unroll
        for (int nr = 0; nr < 2; ++nr)
          acc[mr][nr] = __builtin_amdgcn_mfma_f32_16x16x32_bf16(af[mr], bfr[nr],
                                                                acc[mr][nr], 0, 0, 0);
    }
    __syncthreads();
  }

  // epilogue: C row = m0+wr*64+mr*16+g*4+j, col = n0+wc*32+nr*16+li
#pragma unroll
  for (int nr = 0; nr < 2; ++nr) {
    int col = n0 + wc * 32 + nr * 16 + li;
    float bv = bias[col];
#pragma unroll
    for (int mr = 0; mr < 4; ++mr) {
#pragma unroll
      for (int j = 0; j < 4; ++j) {
        int row = m0 + wr * 64 + mr * 16 + g * 4 + j;
        float v = acc[mr][nr][j] + bv;
        if (MODE == 0) {
          int b = row >> 11, nn = row & 2047, h = col >> 6, dd = col & 63;
          ((u16*)Cout)[(((size_t)(b * 8 + h) << 11) + nn) * 64 + dd] = f2bf(v);
        } else if (MODE == 1) {
          int b = row >> 11, nn = row & 2047, h = col >> 6, dd = col & 63;
          ((u16*)Cout)[(((size_t)(b * 8 + h) * 64) + dd) * 2048 + nn] = f2bf(v);
        } else {
          ((float*)Cout)[(size_t)row * 512 + col] = v;
        }
      }
    }
  }
}

// ---------------- flash attention + Q residual ----------------
// Q,K: [B*H][2048][64] bf16; Vt: [B*H][64][2048] bf16; Ob: [B][2048][512] bf16
// grid: (32 q-tiles, 32 bh). 4 waves x 16 q-rows. KV tile = 64.
__global__ __launch_bounds__(256) void k_attn(const u16* __restrict__ Qb,
                                              const u16* __restrict__ Kb,
                                              const u16* __restrict__ Vt,
                                              u16* __restrict__ Ob) {
  const int tid = threadIdx.x, wid = tid >> 6, lane = tid & 63;
  const int g = lane >> 4, li = lane & 15;
  const int qt = blockIdx.x, bh = blockIdx.y;

  __shared__ __align__(16) u16 Ks[64 * 64];   // swizzled
  __shared__ __align__(16) u16 Vts[64 * 64];  // swizzled
  __shared__ __align__(16) u16 Ps[4][16][72]; // per-wave P transpose buffer

  const u16* Qh = Qb + ((size_t)bh << 11) * 64;
  const u16* Kh = Kb + ((size_t)bh << 11) * 64;
  const u16* Vh = Vt + (size_t)bh * 64 * 2048;

  const int qrow = qt * 64 + wid * 16 + li;  // A-frag row for this lane
  bf16x8 qf[2];
  qf[0] = *(const bf16x8*)(Qh + (size_t)qrow * 64 + g * 8);
  qf[1] = *(const bf16x8*)(Qh + (size_t)qrow * 64 + 32 + g * 8);

  f32x4 oacc[4] = {};
  float mrow[4], lrow[4];
#pragma unroll
  for (int j = 0; j < 4; ++j) { mrow[j] = -3.0e38f; lrow[j] = 0.f; }

  for (int kt = 0; kt < 32; ++kt) {
    const int kv0 = kt * 64;
    // stage K tile (contiguous 8KB in global)
#pragma unroll
    for (int i = 0; i < 2; ++i) {
      int P0 = ((i * 4 + wid) << 10) + lane * 16;
      int L0 = P0 ^ (((P0 >> 7) & 7) << 4);
      gload_lds16((const char*)(Kh + (size_t)kv0 * 64) + L0,
                  (char*)Ks + ((i * 4 + wid) << 10));
    }
    // stage Vt tile (row stride 2048 elems in global)
#pragma unroll
    for (int i = 0; i < 2; ++i) {
      int P0 = ((i * 4 + wid) << 10) + lane * 16;
      int L0 = P0 ^ (((P0 >> 7) & 7) << 4);
      int rr = L0 >> 7, cb = L0 & 127;
      gload_lds16((const char*)Vh + (size_t)rr * 4096 + kv0 * 2 + cb,
                  (char*)Vts + ((i * 4 + wid) << 10));
    }
    asm volatile("s_waitcnt vmcnt(0)" ::: "memory");
    __syncthreads();

    // S = Q K^T  (per wave: 16 q-rows x 64 kv-cols)
    f32x4 s[4] = {};
#pragma unroll
    for (int ks = 0; ks < 2; ++ks) {
#pragma unroll
      for (int ct = 0; ct < 4; ++ct) {
        int row = ct * 16 + li;
        int L = row * 128 + ks * 64 + g * 16;
        int P = L ^ ((row & 7) << 4);
        bf16x8 kf = *(const bf16x8*)((const char*)Ks + P);
        s[ct] = __builtin_amdgcn_mfma_f32_16x16x32_bf16(qf[ks], kf, s[ct], 0, 0, 0);
      }
    }

    // scale + online softmax. Row r = (g*4+j); values spread over 16 lanes of group g.
    float mt[4];
#pragma unroll
    for (int j = 0; j < 4; ++j) {
#pragma unroll
      for (int ct = 0; ct < 4; ++ct) s[ct][j] *= 0.125f;
      mt[j] = fmaxf(fmaxf(s[0][j], s[1][j]), fmaxf(s[2][j], s[3][j]));
    }
#pragma unroll
    for (int mask = 1; mask <= 8; mask <<= 1)
#pragma unroll
      for (int j = 0; j < 4; ++j) mt[j] = fmaxf(mt[j], __shfl_xor(mt[j], mask));

    float pr[4][4], rs[4];
#pragma unroll
    for (int j = 0; j < 4; ++j) {
      float mn = fmaxf(mrow[j], mt[j]);
      float sc = __expf(mrow[j] - mn);
      mrow[j] = mn;
      float sum = 0.f;
#pragma unroll
      for (int ct = 0; ct < 4; ++ct) {
        float p = __expf(s[ct][j] - mn);
        pr[ct][j] = p;
        sum += p;
      }
      rs[j] = sum;
      lrow[j] *= sc;
#pragma unroll
      for (int dt = 0; dt < 4; ++dt) oacc[dt][j] *= sc;
    }
#pragma unroll
    for (int mask = 1; mask <= 8; mask <<= 1)
#pragma unroll
      for (int j = 0; j < 4; ++j) rs[j] += __shfl_xor(rs[j], mask);
#pragma unroll
    for (int j = 0; j < 4; ++j) lrow[j] += rs[j];

    // transpose P through per-wave LDS: C-layout -> A-frag layout
#pragma unroll
    for (int ct = 0; ct < 4; ++ct)
#pragma unroll
      for (int j = 0; j < 4; ++j)
        Ps[wid][g * 4 + j][ct * 16 + li] = f2bf(pr[ct][j]);
    asm volatile("s_waitcnt lgkmcnt(0)" ::: "memory");

    // O += P @ V
#pragma unroll
    for (int ks2 = 0; ks2 < 2; ++ks2) {
      bf16x8 pa = *(const bf16x8*)(&Ps[wid][li][ks2 * 32 + g * 8]);
#pragma unroll
      for (int dt = 0; dt < 4; ++dt) {
        int row = dt * 16 + li;
        int L = row * 128 + ks2 * 64 + g * 16;
        int P = L ^ ((row & 7) << 4);
        bf16x8 vf = *(const bf16x8*)((const char*)Vts + P);
        oacc[dt] = __builtin_amdgcn_mfma_f32_16x16x32_bf16(pa, vf, oacc[dt], 0, 0, 0);
      }
    }
    __syncthreads();
  }

  // epilogue: normalize, add Q residual, write [B][2048][512] bf16
  const int b = bh >> 3, h = bh & 7;
#pragma unroll
  for (int j = 0; j < 4; ++j) {
    int r = qt * 64 + wid * 16 + g * 4 + j;  // seq position
    float inv = 1.0f / lrow[j];
#pragma unroll
    for (int dt = 0; dt < 4; ++dt) {
      int d = dt * 16 + li;
      float qv = bf2f(Qh[(size_t)r * 64 + d]);
      float v = oacc[dt][j] * inv + qv;
      Ob[((size_t)(b * 2048 + r)) * 512 + h * 64 + d] = f2bf(v);
    }
  }
}

// ---------------- launch ----------------
extern "C" void kernel_launch(void* const* d_in, const int* in_sizes, int n_in,
                              void* d_out, int out_size, void* d_ws, size_t ws_size,
                              hipStream_t stream) {
  const float* X  = (const float*)d_in[0];
  const float* Y  = (const float*)d_in[1];
  const float* Wq = (const float*)d_in[2];
  const float* bq = (const float*)d_in[3];
  const float* Wk = (const float*)d_in[4];
  const float* bk = (const float*)d_in[5];
  const float* Wv = (const float*)d_in[6];
  const float* bv = (const float*)d_in[7];
  const float* Wo = (const float*)d_in[8];
  const float* bo = (const float*)d_in[9];

  char* ws = (char*)d_ws;
  u16* Xb  = (u16*)(ws);                       // 8 MB
  u16* Yb  = (u16*)(ws + (size_t)(8  << 20));  // 8 MB
  u16* Wqb = (u16*)(ws + (size_t)(16 << 20));  // 4 x 0.5 MB
  u16* Wkb = Wqb + 262144;
  u16* Wvb = Wkb + 262144;
  u16* Wob = Wvb + 262144;
  u16* Qb  = (u16*)(ws + (size_t)(18 << 20));  // 8 MB [B][H][N][64]
  u16* Kb  = (u16*)(ws + (size_t)(26 << 20));  // 8 MB [B][H][N][64]
  u16* Vtb = (u16*)(ws + (size_t)(34 << 20));  // 8 MB [B][H][64][N]
  u16* Ob  = (u16*)(ws + (size_t)(42 << 20));  // 8 MB [B][N][512]

  k_conv<<<2048, 256, 0, stream>>>(X, Xb, 4194304);
  k_conv<<<2048, 256, 0, stream>>>(Y, Yb, 4194304);
  k_convw<<<512, 256, 0, stream>>>(Wq, Wk, Wv, Wo, Wqb);

  dim3 gg(8, 64);  // N/64 x M/128
  k_gemm<0><<<gg, 256, 0, stream>>>(Xb, Wqb, bq, Qb);
  k_gemm<0><<<gg, 256, 0, stream>>>(Yb, Wkb, bk, Kb);
  k_gemm<1><<<gg, 256, 0, stream>>>(Yb, Wvb, bv, Vtb);

  k_attn<<<dim3(32, 32), 256, 0, stream>>>(Qb, Kb, Vtb, Ob);

  k_gemm<2><<<gg, 256, 0, stream>>>(Ob, Wob, bo, d_out);
}

// Round 2
// 106.467 us; speedup vs baseline: 1.7070x; 1.7070x over previous
//
#include <hip/hip_runtime.h>
#include <hip/hip_bf16.h>

typedef unsigned short u16;
typedef __attribute__((ext_vector_type(4))) float f32x4;
typedef __attribute__((ext_vector_type(16))) float f32x16;
typedef __attribute__((ext_vector_type(8))) short bf16x8;
typedef __attribute__((ext_vector_type(4))) int i32x4;
typedef __attribute__((ext_vector_type(4))) unsigned short u16x4;

#define DEVI static __device__ __forceinline__

DEVI u16 f2bf(float f) {
  __hip_bfloat16 h = __float2bfloat16(f);
  return *reinterpret_cast<u16*>(&h);
}
DEVI float bf2f(u16 u) {
  unsigned int x = ((unsigned int)u) << 16;
  return __uint_as_float(x);
}
DEVI float exp2a(float x) {  // v_exp_f32: 2^x
  float r;
  asm("v_exp_f32 %0, %1" : "=v"(r) : "v"(x));
  return r;
}
DEVI int cvtpk(float lo, float hi) {  // packed f32->bf16 pair
  int r;
  asm("v_cvt_pk_bf16_f32 %0, %1, %2" : "=v"(r) : "v"(lo), "v"(hi));
  return r;
}
DEVI f32x16 mfma32(bf16x8 a, bf16x8 b, f32x16 c) {
  return __builtin_amdgcn_mfma_f32_32x32x16_bf16(a, b, c, 0, 0, 0);
}

// global -> LDS direct DMA, 16B per lane. LDS dest is wave-uniform base + lane*16.
DEVI void gload_lds16(const void* g, void* l) {
  __builtin_amdgcn_global_load_lds(
      (const __attribute__((address_space(1))) unsigned int*)g,
      (__attribute__((address_space(3))) unsigned int*)l, 16, 0, 0);
}

// ---------------- fused f32 -> bf16 conversion (X, Y, 4 weights) ----------------
__global__ __launch_bounds__(256) void k_convall(
    const float* __restrict__ X, const float* __restrict__ Y,
    const float* __restrict__ Wq, const float* __restrict__ Wk,
    const float* __restrict__ Wv, const float* __restrict__ Wo,
    u16* __restrict__ Xb, u16* __restrict__ Yb, u16* __restrict__ Wb) {
  long i = ((long)blockIdx.x * 256 + threadIdx.x) * 8;
  const float* s;
  u16* d;
  long off;
  if (i < 4194304) {
    s = X; d = Xb; off = i;
  } else if (i < 8388608) {
    s = Y; d = Yb; off = i - 4194304;
  } else {
    long w = (i - 8388608) >> 18;
    off = (i - 8388608) & 262143;
    s = w == 0 ? Wq : w == 1 ? Wk : w == 2 ? Wv : Wo;
    d = Wb + w * 262144;
  }
  f32x4 a = *(const f32x4*)(s + off);
  f32x4 b = *(const f32x4*)(s + off + 4);
  bf16x8 v;
#pragma unroll
  for (int j = 0; j < 4; ++j) {
    v[j]     = (short)f2bf(a[j]);
    v[4 + j] = (short)f2bf(b[j]);
  }
  *(bf16x8*)(d + off) = v;
}

// ---------------- GEMM core (BM=128 BN=64 BK=64, 4 waves 2x2) ----------------
// Computes acc for C[M][512] = A @ W^T; caller handles epilogue via template/branch.
struct GemmAcc { f32x4 acc[4][2]; };

DEVI void gemm_body(const u16* __restrict__ A, const u16* __restrict__ Bw,
                    int m0, int n0, u16* As, u16* Bs, GemmAcc& G) {
  constexpr int K = 512;
  const int tid = threadIdx.x;
  const int wid = tid >> 6, lane = tid & 63;
  const int g = lane >> 4, li = lane & 15;
  const int wr = wid >> 1, wc = wid & 1;

#pragma unroll
  for (int mr = 0; mr < 4; ++mr)
#pragma unroll
    for (int nr = 0; nr < 2; ++nr) G.acc[mr][nr] = (f32x4){0.f, 0.f, 0.f, 0.f};

  for (int kt = 0; kt < K / 64; ++kt) {
    const int k0 = kt * 64;
#pragma unroll
    for (int i = 0; i < 4; ++i) {
      int P0 = ((i * 4 + wid) << 10) + lane * 16;
      int L0 = P0 ^ (((P0 >> 7) & 7) << 4);
      int row = L0 >> 7, colb = L0 & 127;
      gload_lds16((const char*)A + ((size_t)(m0 + row) * K + k0) * 2 + colb,
                  (char*)As + ((i * 4 + wid) << 10));
    }
#pragma unroll
    for (int i = 0; i < 2; ++i) {
      int P0 = ((i * 4 + wid) << 10) + lane * 16;
      int L0 = P0 ^ (((P0 >> 7) & 7) << 4);
      int row = L0 >> 7, colb = L0 & 127;
      gload_lds16((const char*)Bw + ((size_t)(n0 + row) * K + k0) * 2 + colb,
                  (char*)Bs + ((i * 4 + wid) << 10));
    }
    asm volatile("s_waitcnt vmcnt(0)" ::: "memory");
    __syncthreads();

#pragma unroll
    for (int ks = 0; ks < 2; ++ks) {
      bf16x8 af[4], bfr[2];
#pragma unroll
      for (int mr = 0; mr < 4; ++mr) {
        int row = wr * 64 + mr * 16 + li;
        int L = row * 128 + ks * 64 + g * 16;
        int P = L ^ ((row & 7) << 4);
        af[mr] = *(const bf16x8*)((const char*)As + P);
      }
#pragma unroll
      for (int nr = 0; nr < 2; ++nr) {
        int row = wc * 32 + nr * 16 + li;
        int L = row * 128 + ks * 64 + g * 16;
        int P = L ^ ((row & 7) << 4);
        bfr[nr] = *(const bf16x8*)((const char*)Bs + P);
      }
#pragma unroll
      for (int mr = 0; mr < 4; ++mr)
#pragma unroll
        for (int nr = 0; nr < 2; ++nr)
          G.acc[mr][nr] = __builtin_amdgcn_mfma_f32_16x16x32_bf16(
              af[mr], bfr[nr], G.acc[mr][nr], 0, 0, 0);
    }
    __syncthreads();
  }
}

// Fused QKV projection: z=0 -> Q [B][H][N][64], z=1 -> K same, z=2 -> V^T [B][H][64][N]
__global__ __launch_bounds__(256) void k_gemm_qkv(
    const u16* __restrict__ Xb, const u16* __restrict__ Yb,
    const u16* __restrict__ Wall, const float* __restrict__ bq,
    const float* __restrict__ bk, const float* __restrict__ bv,
    u16* __restrict__ Qb, u16* __restrict__ Kb, u16* __restrict__ Vtb) {
  __shared__ __align__(16) u16 As[128 * 64];
  __shared__ __align__(16) u16 Bs[64 * 64];
  const int z = blockIdx.z;
  const u16* A = z == 0 ? Xb : Yb;
  const u16* Bw = Wall + (size_t)z * 262144;
  const float* bias = z == 0 ? bq : (z == 1 ? bk : bv);
  u16* Cout = z == 0 ? Qb : (z == 1 ? Kb : Vtb);

  int lin = blockIdx.x + 8 * blockIdx.y;
  int xcd = lin & 7, slot = lin >> 3;
  int by = xcd * 8 + (slot >> 3), bx = slot & 7;
  const int m0 = by * 128, n0 = bx * 64;

  GemmAcc G;
  gemm_body(A, Bw, m0, n0, As, Bs, G);

  const int tid = threadIdx.x;
  const int wid = tid >> 6, lane = tid & 63;
  const int g = lane >> 4, li = lane & 15;
  const int wr = wid >> 1, wc = wid & 1;
#pragma unroll
  for (int nr = 0; nr < 2; ++nr) {
    int col = n0 + wc * 32 + nr * 16 + li;
    float bvv = bias[col];
#pragma unroll
    for (int mr = 0; mr < 4; ++mr) {
#pragma unroll
      for (int j = 0; j < 4; ++j) {
        int row = m0 + wr * 64 + mr * 16 + g * 4 + j;
        float v = G.acc[mr][nr][j] + bvv;
        int b = row >> 11, nn = row & 2047, h = col >> 6, dd = col & 63;
        if (z <= 1)
          Cout[(((size_t)(b * 8 + h) << 11) + nn) * 64 + dd] = f2bf(v);
        else
          Cout[(((size_t)(b * 8 + h) * 64) + dd) * 2048 + nn] = f2bf(v);
      }
    }
  }
}

// Final projection: f32 row-major output [M][512]
__global__ __launch_bounds__(256) void k_gemm_out(const u16* __restrict__ A,
                                                  const u16* __restrict__ Bw,
                                                  const float* __restrict__ bias,
                                                  float* __restrict__ Cout) {
  __shared__ __align__(16) u16 As[128 * 64];
  __shared__ __align__(16) u16 Bs[64 * 64];
  int lin = blockIdx.x + 8 * blockIdx.y;
  int xcd = lin & 7, slot = lin >> 3;
  int by = xcd * 8 + (slot >> 3), bx = slot & 7;
  const int m0 = by * 128, n0 = bx * 64;

  GemmAcc G;
  gemm_body(A, Bw, m0, n0, As, Bs, G);

  const int tid = threadIdx.x;
  const int wid = tid >> 6, lane = tid & 63;
  const int g = lane >> 4, li = lane & 15;
  const int wr = wid >> 1, wc = wid & 1;
#pragma unroll
  for (int nr = 0; nr < 2; ++nr) {
    int col = n0 + wc * 32 + nr * 16 + li;
    float bvv = bias[col];
#pragma unroll
    for (int mr = 0; mr < 4; ++mr) {
#pragma unroll
      for (int j = 0; j < 4; ++j) {
        int row = m0 + wr * 64 + mr * 16 + g * 4 + j;
        Cout[(size_t)row * 512 + col] = G.acc[mr][nr][j] + bvv;
      }
    }
  }
}

// ---------------- flash attention, 32x32 MFMA, swapped QK^T ----------------
// Q,K: [B*H][2048][64] bf16; Vt: [B*H][64][2048] bf16; Ob: [B][2048][512] bf16
// 512 blocks (XCD-swizzled), 4 waves x 32 q-rows = 128 q-rows/block. KV tile 64, dbuf.
template <int KB, int VB>
DEVI void attn_tile(const char* L, const int* vK, const bf16x8* qf, f32x16& o0,
                    f32x16& o1, float& mrow, float& lrow) {
  const float C2 = 0.18033688f;  // 0.125 * log2(e)
  const f32x16 Z = {};
  f32x16 s0, s1;
  bf16x8 kf;
  // QK^T: S^T[kv][q], kv rows t32*32 + (reg&3)+8*(reg>>2)+4h, col q = li
  kf = *(const bf16x8*)(L + (vK[0] + KB));        s0 = mfma32(kf, qf[0], Z);
  kf = *(const bf16x8*)(L + (vK[1] + KB));        s0 = mfma32(kf, qf[1], s0);
  kf = *(const bf16x8*)(L + (vK[2] + KB));        s0 = mfma32(kf, qf[2], s0);
  kf = *(const bf16x8*)(L + (vK[3] + KB));        s0 = mfma32(kf, qf[3], s0);
  kf = *(const bf16x8*)(L + (vK[0] + KB + 4096)); s1 = mfma32(kf, qf[0], Z);
  kf = *(const bf16x8*)(L + (vK[1] + KB + 4096)); s1 = mfma32(kf, qf[1], s1);
  kf = *(const bf16x8*)(L + (vK[2] + KB + 4096)); s1 = mfma32(kf, qf[2], s1);
  kf = *(const bf16x8*)(L + (vK[3] + KB + 4096)); s1 = mfma32(kf, qf[3], s1);

  // in-lane max over 32 (raw S), then cross-h
  float mx[8];
#pragma unroll
  for (int i = 0; i < 8; ++i)
    mx[i] = fmaxf(fmaxf(s0[2 * i], s0[2 * i + 1]), fmaxf(s1[2 * i], s1[2 * i + 1]));
  float mt = fmaxf(fmaxf(fmaxf(mx[0], mx[1]), fmaxf(mx[2], mx[3])),
                   fmaxf(fmaxf(mx[4], mx[5]), fmaxf(mx[6], mx[7])));
  mt = fmaxf(mt, __shfl_xor(mt, 32));
  float mnew = fmaxf(mrow, mt);
  float sc = exp2a((mrow - mnew) * C2);
  float negmC = -mnew * C2;
  mrow = mnew;
  // p = exp2(C2*s - C2*m), overwrite s
#pragma unroll
  for (int i = 0; i < 16; ++i) s0[i] = exp2a(fmaf(s0[i], C2, negmC));
#pragma unroll
  for (int i = 0; i < 16; ++i) s1[i] = exp2a(fmaf(s1[i], C2, negmC));
  // row sum (tree) + cross-h
  float t8[8];
#pragma unroll
  for (int i = 0; i < 8; ++i)
    t8[i] = (s0[2 * i] + s0[2 * i + 1]) + (s1[2 * i] + s1[2 * i + 1]);
  float rs = ((t8[0] + t8[1]) + (t8[2] + t8[3])) + ((t8[4] + t8[5]) + (t8[6] + t8[7]));
  rs += __shfl_xor(rs, 32);
  lrow = lrow * sc + rs;
  // rescale O
#pragma unroll
  for (int i = 0; i < 16; ++i) o0[i] *= sc;
#pragma unroll
  for (int i = 0; i < 16; ++i) o1[i] *= sc;

  // PV: pack P to B-frag via cvt_pk + permlane32_swap, then mfma with Vt
#pragma unroll
  for (int kt16 = 0; kt16 < 4; ++kt16) {
    const f32x16& sp = (kt16 & 2) ? s1 : s0;
    const int base = (kt16 & 1) * 8;
    int a0 = cvtpk(sp[base + 0], sp[base + 1]);
    int a1 = cvtpk(sp[base + 2], sp[base + 3]);
    int b0 = cvtpk(sp[base + 4], sp[base + 5]);
    int b1 = cvtpk(sp[base + 6], sp[base + 7]);
    asm volatile("v_permlane32_swap_b32 %0, %1" : "+v"(a0), "+v"(b0));
    asm volatile("v_permlane32_swap_b32 %0, %1" : "+v"(a1), "+v"(b1));
    i32x4 pi = {a0, a1, b0, b1};
    bf16x8 pb = __builtin_bit_cast(bf16x8, pi);
    bf16x8 va = *(const bf16x8*)(L + (vK[kt16] + VB));
    o0 = mfma32(va, pb, o0);
    va = *(const bf16x8*)(L + (vK[kt16] + VB + 4096));
    o1 = mfma32(va, pb, o1);
  }
}

__global__ __launch_bounds__(256, 2) void k_attn(const u16* __restrict__ Qb,
                                                 const u16* __restrict__ Kb,
                                                 const u16* __restrict__ Vt,
                                                 u16* __restrict__ Ob) {
  __shared__ __align__(16) u16 lds[16384];  // [2 buf][K 8KB | V 8KB] = 32KB
  const int tid = threadIdx.x, wid = tid >> 6, lane = tid & 63;
  const int li = lane & 31, h = lane >> 5;

  // XCD swizzle: 512 blocks -> xcd gets 4 bh x 16 qt contiguous
  const int lin = blockIdx.x;
  const int xcd = lin & 7, slot = lin >> 3;
  const int bh = xcd * 4 + (slot >> 4);
  const int qt = slot & 15;

  const u16* Qh = Qb + ((size_t)bh << 11) * 64;
  const u16* Kh = Kb + ((size_t)bh << 11) * 64;
  const u16* Vh = Vt + (size_t)bh * 64 * 2048;

  // per-lane LDS read offsets (kt-invariant): li*128 + ((kt16*32+h*16)^swz)
  const int swz = (li & 7) << 4;
  int vK[4];
#pragma unroll
  for (int k4 = 0; k4 < 4; ++k4) vK[k4] = li * 128 + ((k4 * 32 + h * 16) ^ swz);

  // Q fragment (B-operand): q = qr0+li, d = kt16*16 + h*8 + e
  const int qr0 = qt * 128 + wid * 32;
  const int q = qr0 + li;
  bf16x8 qf[4];
#pragma unroll
  for (int k4 = 0; k4 < 4; ++k4)
    qf[k4] = *(const bf16x8*)(Qh + (size_t)q * 64 + k4 * 16 + h * 8);

  // staging pointers (inverse-swizzled source, linear LDS dest)
  int P0a = (wid << 10) + lane * 16;
  int L0a = P0a ^ (((P0a >> 7) & 7) << 4);
  int P0b = ((4 + wid) << 10) + lane * 16;
  int L0b = P0b ^ (((P0b >> 7) & 7) << 4);
  const char* pK0 = (const char*)Kh + L0a;
  const char* pK1 = (const char*)Kh + L0b;
  const char* pV0 = (const char*)Vh + (L0a >> 7) * 4096 + (L0a & 127);
  const char* pV1 = (const char*)Vh + (L0b >> 7) * 4096 + (L0b & 127);
  char* lb = (char*)lds;

  auto STAGE = [&](int bb) {
    gload_lds16(pK0, lb + bb + (wid << 10));
    gload_lds16(pK1, lb + bb + ((4 + wid) << 10));
    gload_lds16(pV0, lb + 16384 + bb + (wid << 10));
    gload_lds16(pV1, lb + 16384 + bb + ((4 + wid) << 10));
    pK0 += 8192; pK1 += 8192; pV0 += 128; pV1 += 128;
  };

  f32x16 o0 = {}, o1 = {};
  float mrow = -3.0e38f, lrow = 0.f;
  const char* L = (const char*)lds;

  STAGE(0);
  asm volatile("s_waitcnt vmcnt(0)" ::: "memory");
  __syncthreads();

#pragma unroll 1
  for (int kt = 0; kt < 32; kt += 2) {
    STAGE(8192);  // tile kt+1 -> buf1
    attn_tile<0, 16384>(L, vK, qf, o0, o1, mrow, lrow);
    asm volatile("s_waitcnt vmcnt(0)" ::: "memory");
    __syncthreads();
    if (kt < 30) STAGE(0);  // tile kt+2 -> buf0
    attn_tile<8192, 24576>(L, vK, qf, o0, o1, mrow, lrow);
    asm volatile("s_waitcnt vmcnt(0)" ::: "memory");
    __syncthreads();
  }

  // epilogue: normalize, Q residual, write [B][2048][512] bf16
  const int b = bh >> 3, head = bh & 7;
  const float inv = 1.0f / lrow;
  u16* orow = Ob + ((size_t)(b * 2048 + q)) * 512 + head * 64;
  const u16* qrow = Qh + (size_t)q * 64;
#pragma unroll
  for (int dt = 0; dt < 2; ++dt) {
    const f32x16& o = dt ? o1 : o0;
#pragma unroll
    for (int s2 = 0; s2 < 4; ++s2) {
      int d0 = dt * 32 + s2 * 8 + h * 4;
      u16x4 qv = *(const u16x4*)(qrow + d0);
      u16x4 w;
#pragma unroll
      for (int j = 0; j < 4; ++j)
        w[j] = f2bf(fmaf(o[s2 * 4 + j], inv, bf2f(qv[j])));
      *(u16x4*)(orow + d0) = w;
    }
  }
}

// ---------------- launch ----------------
extern "C" void kernel_launch(void* const* d_in, const int* in_sizes, int n_in,
                              void* d_out, int out_size, void* d_ws, size_t ws_size,
                              hipStream_t stream) {
  const float* X  = (const float*)d_in[0];
  const float* Y  = (const float*)d_in[1];
  const float* Wq = (const float*)d_in[2];
  const float* bq = (const float*)d_in[3];
  const float* Wk = (const float*)d_in[4];
  const float* bk = (const float*)d_in[5];
  const float* Wv = (const float*)d_in[6];
  const float* bv = (const float*)d_in[7];
  const float* Wo = (const float*)d_in[8];
  const float* bo = (const float*)d_in[9];

  char* ws = (char*)d_ws;
  u16* Xb  = (u16*)(ws);                       // 8 MB
  u16* Yb  = (u16*)(ws + (size_t)(8  << 20));  // 8 MB
  u16* Wb  = (u16*)(ws + (size_t)(16 << 20));  // 4 x 0.5 MB (Wq,Wk,Wv,Wo)
  u16* Qb  = (u16*)(ws + (size_t)(18 << 20));  // 8 MB [B][H][N][64]
  u16* Kb  = (u16*)(ws + (size_t)(26 << 20));  // 8 MB [B][H][N][64]
  u16* Vtb = (u16*)(ws + (size_t)(34 << 20));  // 8 MB [B][H][64][N]
  u16* Ob  = (u16*)(ws + (size_t)(42 << 20));  // 8 MB [B][N][512]

  k_convall<<<4608, 256, 0, stream>>>(X, Y, Wq, Wk, Wv, Wo, Xb, Yb, Wb);

  k_gemm_qkv<<<dim3(8, 64, 3), 256, 0, stream>>>(Xb, Yb, Wb, bq, bk, bv, Qb, Kb, Vtb);

  k_attn<<<512, 256, 0, stream>>>(Qb, Kb, Vtb, Ob);

  k_gemm_out<<<dim3(8, 64), 256, 0, stream>>>(Ob, Wb + 3 * 262144, bo, (float*)d_out);
}